// Round 1
// baseline (5109.419 us; speedup 1.0000x reference)
//
#include <hip/hip_runtime.h>

#define NN 100000
#define NE 3200000
#define NB 512
#define SCHUNK 1024
#define NCHUNK ((NN + SCHUNK - 1) / SCHUNK) // 98

// ---------------- degree histogram ----------------
__global__ void k_degrees(const int* __restrict__ a0, const int* __restrict__ a1,
                          const int* __restrict__ a2, const int* __restrict__ a3,
                          int* __restrict__ deg) {
    int arr = blockIdx.y;
    const int* p = (arr == 0) ? a0 : (arr == 1) ? a1 : (arr == 2) ? a2 : a3;
    int i = blockIdx.x * 256 + threadIdx.x;
    if (i < NE) atomicAdd(deg + arr * NN + p[i], 1);
}

// deg(int) -> rsqrt(max(deg,1)) (float), in place
__global__ void k_norms(void* __restrict__ buf) {
    int i = blockIdx.x * 256 + threadIdx.x;
    if (i < 4 * NN) {
        int d = ((const int*)buf)[i];
        ((float*)buf)[i] = rsqrtf(fmaxf((float)d, 1.0f));
    }
}

// ---------------- exclusive scan (3 phases) ----------------
__global__ void k_chunk_sum(const int* __restrict__ deg, int* __restrict__ chunksum) {
    __shared__ int s[256];
    int c = blockIdx.x, t = threadIdx.x;
    int base = c * SCHUNK + t * 4;
    int sum = 0;
#pragma unroll
    for (int i = 0; i < 4; i++) { int idx = base + i; if (idx < NN) sum += deg[idx]; }
    s[t] = sum; __syncthreads();
    for (int d = 128; d > 0; d >>= 1) { if (t < d) s[t] += s[t + d]; __syncthreads(); }
    if (t == 0) chunksum[c] = s[0];
}

__global__ void k_chunk_scan(const int* __restrict__ chunksum, int* __restrict__ chunkoff,
                             int* __restrict__ off) {
    if (threadIdx.x == 0) {
        int acc = 0;
        for (int i = 0; i < NCHUNK; i++) { chunkoff[i] = acc; acc += chunksum[i]; }
        chunkoff[NCHUNK] = acc;
        off[NN] = acc; // total = NE
    }
}

__global__ void k_scan_write(const int* __restrict__ deg, const int* __restrict__ chunkoff,
                             int* __restrict__ off) {
    __shared__ int s[256];
    int c = blockIdx.x, t = threadIdx.x;
    int base = c * SCHUNK + t * 4;
    int v[4]; int sum = 0;
#pragma unroll
    for (int i = 0; i < 4; i++) { int idx = base + i; v[i] = (idx < NN) ? deg[idx] : 0; sum += v[i]; }
    s[t] = sum; __syncthreads();
    for (int d = 1; d < 256; d <<= 1) {
        int add = (t >= d) ? s[t - d] : 0;
        __syncthreads();
        s[t] += add;
        __syncthreads();
    }
    int run = chunkoff[c] + (s[t] - sum); // exclusive prefix for this thread
#pragma unroll
    for (int i = 0; i < 4; i++) {
        int idx = base + i;
        if (idx < NN) off[idx] = run;
        run += v[i];
    }
}

__global__ void k_copy_cursor(const int* __restrict__ off0, const int* __restrict__ off1,
                              int* __restrict__ cur0, int* __restrict__ cur1) {
    int i = blockIdx.x * 256 + threadIdx.x;
    if (i < NN) {
        if (blockIdx.y == 0) cur0[i] = off0[i];
        else                 cur1[i] = off1[i];
    }
}

__global__ void k_fill(const int* __restrict__ src, const int* __restrict__ dst,
                       int* __restrict__ cursor, int* __restrict__ edges) {
    int e = blockIdx.x * 256 + threadIdx.x;
    if (e < NE) {
        int d = dst[e];
        int pos = atomicAdd(cursor + d, 1);
        edges[pos] = src[e];
    }
}

// ---------------- feature transform: h = (x * sn) @ W ----------------
template <int IN, int OUT>
__global__ void k_transform(const float* __restrict__ in, int in_stride,
                            const float* __restrict__ sn, const float* __restrict__ W,
                            float* __restrict__ h) {
    constexpr int ROWS = 256 / OUT;
    __shared__ float sW[IN * OUT];
    __shared__ float sx[ROWS * IN];
    int t = threadIdx.x;
    int node0 = blockIdx.x * ROWS;
    for (int i = t; i < IN * OUT; i += 256) sW[i] = W[i];
    for (int i = t; i < ROWS * IN; i += 256) {
        int r = i / IN, k = i % IN;
        int node = node0 + r;
        sx[i] = (node < NN) ? in[(size_t)node * in_stride + k] : 0.0f;
    }
    __syncthreads();
    int r = t / OUT, c = t % OUT;
    int node = node0 + r;
    if (node < NN) {
        float acc = 0.0f;
#pragma unroll
        for (int k = 0; k < IN; k++) acc += sx[r * IN + k] * sW[k * OUT + c];
        h[(size_t)node * OUT + c] = acc * sn[node];
    }
}

// ---------------- CSR gather aggregation: out = agg*dn + b (opt relu) ----------------
template <int OUT, int RELU>
__global__ void k_aggregate(const float* __restrict__ h, const int* __restrict__ off,
                            const int* __restrict__ edges, const float* __restrict__ dn,
                            const float* __restrict__ bias, float* __restrict__ out,
                            int col_off) {
    constexpr int NPB = 256 / OUT;
    int t = threadIdx.x;
    int g = t / OUT, c = t % OUT;
    int node = blockIdx.x * NPB + g;
    if (node >= NN) return;
    int e0 = off[node], e1 = off[node + 1];
    float acc = 0.0f;
    for (int e = e0; e < e1; e++) {
        int s = edges[e];
        acc += h[(size_t)s * OUT + c];
    }
    float v = acc * dn[node] + bias[c];
    if (RELU) v = fmaxf(v, 0.0f);
    out[(size_t)node * 48 + col_off + c] = v;
}

// ---------------- pooling: pooled[b, col_off+j] += sum_k len[b,k]*H[k,j] ----------------
#define KCH 3125 // 100000 / 32
__global__ void k_pool(const float* __restrict__ len, const float* __restrict__ Hm,
                       float* __restrict__ pooled, int col_off) {
    int t = threadIdx.x;          // 384 threads
    int bl = t / 48, j = t % 48;  // 8 rows x 48 cols
    int b = blockIdx.x * 8 + bl;
    int k0 = blockIdx.y * KCH;
    int k1 = k0 + KCH; if (k1 > NN) k1 = NN;
    const float* lrow = len + (size_t)b * NN;
    float acc = 0.0f;
    for (int k = k0; k < k1; k++) acc += lrow[k] * Hm[(size_t)k * 48 + j];
    atomicAdd(&pooled[b * 96 + col_off + j], acc);
}

// ---------------- MLP head ----------------
__global__ void k_mlp(const float* __restrict__ pooled,
                      const float* __restrict__ fc1w, const float* __restrict__ fc1b,
                      const float* __restrict__ fc2w, const float* __restrict__ fc2b,
                      const float* __restrict__ fc3w, const float* __restrict__ fc3b,
                      float* __restrict__ out) {
    __shared__ float srow[96];
    __shared__ float sh[64];
    __shared__ float sh2[16];
    int b = blockIdx.x, t = threadIdx.x; // 64 threads
    srow[t] = pooled[b * 96 + t];
    if (t < 32) srow[64 + t] = pooled[b * 96 + 64 + t];
    __syncthreads();
    float acc = fc1b[t];
    for (int k = 0; k < 96; k++) acc += srow[k] * fc1w[k * 64 + t];
    sh[t] = fmaxf(acc, 0.0f);
    __syncthreads();
    if (t < 16) {
        float a2 = fc2b[t];
        for (int k = 0; k < 64; k++) a2 += sh[k] * fc2w[k * 16 + t];
        sh2[t] = fmaxf(a2, 0.0f);
    }
    __syncthreads();
    if (t == 0) {
        float a3 = fc3b[0];
        for (int k = 0; k < 16; k++) a3 += sh2[k] * fc3w[k];
        out[b] = a3;
    }
}

extern "C" void kernel_launch(void* const* d_in, const int* in_sizes, int n_in,
                              void* d_out, int out_size, void* d_ws, size_t ws_size,
                              hipStream_t stream) {
    const float* solute_x  = (const float*)d_in[0];
    const float* solvent_x = (const float*)d_in[1];
    const float* su_len    = (const float*)d_in[2];
    const float* sv_len    = (const float*)d_in[3];
    const int*   su_src    = (const int*)d_in[4];
    const int*   su_dst    = (const int*)d_in[5];
    const int*   sv_src    = (const int*)d_in[6];
    const int*   sv_dst    = (const int*)d_in[7];
    const float* W1  = (const float*)d_in[8];
    const float* b1  = (const float*)d_in[9];
    const float* W2  = (const float*)d_in[10];
    const float* b2  = (const float*)d_in[11];
    const float* fc1w = (const float*)d_in[12];
    const float* fc1b = (const float*)d_in[13];
    const float* fc2w = (const float*)d_in[14];
    const float* fc2b = (const float*)d_in[15];
    const float* fc3w = (const float*)d_in[16];
    const float* fc3b = (const float*)d_in[17];
    float* out = (float*)d_out;

    // workspace layout (elements of 4 bytes); total ~20.1M elems ~= 80.3 MB
    char* ws = (char*)d_ws;
    size_t o = 0;
    auto alloc = [&](size_t elems) { void* p = ws + o * 4; o += elems; return p; };
    void* degnorm   = alloc(4 * NN);          // int degrees -> float norms (in place)
    int* off_su     = (int*)alloc(NN + 64);
    int* off_sv     = (int*)alloc(NN + 64);
    int* cur_su     = (int*)alloc(NN);
    int* cur_sv     = (int*)alloc(NN);
    int* chunksum   = (int*)alloc(128);
    int* chunkoff   = (int*)alloc(160);
    int* edges_su   = (int*)alloc(NE);
    int* edges_sv   = (int*)alloc(NE);
    float* h_pre    = (float*)alloc(NN * 32);
    float* su_cat   = (float*)alloc((size_t)NN * 48);
    float* sv_cat   = (float*)alloc((size_t)NN * 48);
    float* pooled   = (float*)alloc(NB * 96);

    float* norm = (float*)degnorm;
    float* su_sn = norm + 0 * NN;
    float* su_dn = norm + 1 * NN;
    float* sv_sn = norm + 2 * NN;
    float* sv_dn = norm + 3 * NN;
    int* deg = (int*)degnorm;

    // zero degree counters and pooled accumulator
    hipMemsetAsync(degnorm, 0, 4 * NN * 4, stream);
    hipMemsetAsync(pooled, 0, NB * 96 * 4, stream);

    // degrees for all 4 index arrays
    {
        dim3 g(NE / 256, 4);
        k_degrees<<<g, 256, 0, stream>>>(su_src, su_dst, sv_src, sv_dst, deg);
    }
    // CSR offsets from dst degrees (before norms clobber deg)
    k_chunk_sum<<<NCHUNK, 256, 0, stream>>>(deg + 1 * NN, chunksum);
    k_chunk_scan<<<1, 64, 0, stream>>>(chunksum, chunkoff, off_su);
    k_scan_write<<<NCHUNK, 256, 0, stream>>>(deg + 1 * NN, chunkoff, off_su);
    k_chunk_sum<<<NCHUNK, 256, 0, stream>>>(deg + 3 * NN, chunksum);
    k_chunk_scan<<<1, 64, 0, stream>>>(chunksum, chunkoff, off_sv);
    k_scan_write<<<NCHUNK, 256, 0, stream>>>(deg + 3 * NN, chunkoff, off_sv);

    // degrees -> norms (in place, after scans consumed int degs)
    k_norms<<<(4 * NN + 255) / 256, 256, 0, stream>>>(degnorm);

    // CSR fill
    {
        dim3 g((NN + 255) / 256, 2);
        k_copy_cursor<<<g, 256, 0, stream>>>(off_su, off_sv, cur_su, cur_sv);
    }
    k_fill<<<NE / 256, 256, 0, stream>>>(su_src, su_dst, cur_su, edges_su);
    k_fill<<<NE / 256, 256, 0, stream>>>(sv_src, sv_dst, cur_sv, edges_sv);

    // ---- solute GCN ----
    k_transform<64, 32><<<(NN + 7) / 8, 256, 0, stream>>>(solute_x, 64, su_sn, W1, h_pre);
    k_aggregate<32, 1><<<(NN + 7) / 8, 256, 0, stream>>>(h_pre, off_su, edges_su, su_dn, b1, su_cat, 0);
    k_transform<32, 16><<<(NN + 15) / 16, 256, 0, stream>>>(su_cat, 48, su_sn, W2, h_pre);
    k_aggregate<16, 0><<<(NN + 15) / 16, 256, 0, stream>>>(h_pre, off_su, edges_su, su_dn, b2, su_cat, 32);

    // ---- solvent GCN ----
    k_transform<64, 32><<<(NN + 7) / 8, 256, 0, stream>>>(solvent_x, 64, sv_sn, W1, h_pre);
    k_aggregate<32, 1><<<(NN + 7) / 8, 256, 0, stream>>>(h_pre, off_sv, edges_sv, sv_dn, b1, sv_cat, 0);
    k_transform<32, 16><<<(NN + 15) / 16, 256, 0, stream>>>(sv_cat, 48, sv_sn, W2, h_pre);
    k_aggregate<16, 0><<<(NN + 15) / 16, 256, 0, stream>>>(h_pre, off_sv, edges_sv, sv_dn, b2, sv_cat, 32);

    // ---- fused pooling: each len matrix read exactly once ----
    {
        dim3 g(NB / 8, 32);
        k_pool<<<g, 384, 0, stream>>>(su_len, su_cat, pooled, 0);
        k_pool<<<g, 384, 0, stream>>>(sv_len, sv_cat, pooled, 48);
    }

    // ---- MLP head ----
    k_mlp<<<NB, 64, 0, stream>>>(pooled, fc1w, fc1b, fc2w, fc2b, fc3w, fc3b, out);
}

// Round 2
// 2133.295 us; speedup vs baseline: 2.3951x; 2.3951x over previous
//
#include <hip/hip_runtime.h>

#define NN 100000
#define NE 3200000
#define NB 512
#define SCHUNK 1024
#define NCHUNK ((NN + SCHUNK - 1) / SCHUNK) // 98
#define KCHUNK 6400
#define NKC ((NN + KCHUNK - 1) / KCHUNK)    // 16

// ---------------- degree histogram ----------------
__global__ void k_degrees(const int* __restrict__ a0, const int* __restrict__ a1,
                          const int* __restrict__ a2, const int* __restrict__ a3,
                          int* __restrict__ deg) {
    int arr = blockIdx.y;
    const int* p = (arr == 0) ? a0 : (arr == 1) ? a1 : (arr == 2) ? a2 : a3;
    int i = blockIdx.x * 256 + threadIdx.x;
    if (i < NE) atomicAdd(deg + arr * NN + p[i], 1);
}

// deg(int) -> rsqrt(max(deg,1)) (float), in place
__global__ void k_norms(void* __restrict__ buf) {
    int i = blockIdx.x * 256 + threadIdx.x;
    if (i < 4 * NN) {
        int d = ((const int*)buf)[i];
        ((float*)buf)[i] = rsqrtf(fmaxf((float)d, 1.0f));
    }
}

// ---------------- exclusive scan (3 phases) ----------------
__global__ void k_chunk_sum(const int* __restrict__ deg, int* __restrict__ chunksum) {
    __shared__ int s[256];
    int c = blockIdx.x, t = threadIdx.x;
    int base = c * SCHUNK + t * 4;
    int sum = 0;
#pragma unroll
    for (int i = 0; i < 4; i++) { int idx = base + i; if (idx < NN) sum += deg[idx]; }
    s[t] = sum; __syncthreads();
    for (int d = 128; d > 0; d >>= 1) { if (t < d) s[t] += s[t + d]; __syncthreads(); }
    if (t == 0) chunksum[c] = s[0];
}

__global__ void k_chunk_scan(const int* __restrict__ chunksum, int* __restrict__ chunkoff,
                             int* __restrict__ off) {
    if (threadIdx.x == 0) {
        int acc = 0;
        for (int i = 0; i < NCHUNK; i++) { chunkoff[i] = acc; acc += chunksum[i]; }
        chunkoff[NCHUNK] = acc;
        off[NN] = acc; // total = NE
    }
}

__global__ void k_scan_write(const int* __restrict__ deg, const int* __restrict__ chunkoff,
                             int* __restrict__ off) {
    __shared__ int s[256];
    int c = blockIdx.x, t = threadIdx.x;
    int base = c * SCHUNK + t * 4;
    int v[4]; int sum = 0;
#pragma unroll
    for (int i = 0; i < 4; i++) { int idx = base + i; v[i] = (idx < NN) ? deg[idx] : 0; sum += v[i]; }
    s[t] = sum; __syncthreads();
    for (int d = 1; d < 256; d <<= 1) {
        int add = (t >= d) ? s[t - d] : 0;
        __syncthreads();
        s[t] += add;
        __syncthreads();
    }
    int run = chunkoff[c] + (s[t] - sum); // exclusive prefix for this thread
#pragma unroll
    for (int i = 0; i < 4; i++) {
        int idx = base + i;
        if (idx < NN) off[idx] = run;
        run += v[i];
    }
}

__global__ void k_copy_cursor(const int* __restrict__ off0, const int* __restrict__ off1,
                              int* __restrict__ cur0, int* __restrict__ cur1) {
    int i = blockIdx.x * 256 + threadIdx.x;
    if (i < NN) {
        if (blockIdx.y == 0) cur0[i] = off0[i];
        else                 cur1[i] = off1[i];
    }
}

__global__ void k_fill(const int* __restrict__ src, const int* __restrict__ dst,
                       int* __restrict__ cursor, int* __restrict__ edges) {
    int e = blockIdx.x * 256 + threadIdx.x;
    if (e < NE) {
        int d = dst[e];
        int pos = atomicAdd(cursor + d, 1);
        edges[pos] = src[e];
    }
}

// ---------------- feature transform: h = (x * sn) @ W ----------------
template <int IN, int OUT>
__global__ void k_transform(const float* __restrict__ in, int in_stride,
                            const float* __restrict__ sn, const float* __restrict__ W,
                            float* __restrict__ h) {
    constexpr int ROWS = 256 / OUT;
    __shared__ float sW[IN * OUT];
    __shared__ float sx[ROWS * IN];
    int t = threadIdx.x;
    int node0 = blockIdx.x * ROWS;
    for (int i = t; i < IN * OUT; i += 256) sW[i] = W[i];
    for (int i = t; i < ROWS * IN; i += 256) {
        int r = i / IN, k = i % IN;
        int node = node0 + r;
        sx[i] = (node < NN) ? in[(size_t)node * in_stride + k] : 0.0f;
    }
    __syncthreads();
    int r = t / OUT, c = t % OUT;
    int node = node0 + r;
    if (node < NN) {
        float acc = 0.0f;
#pragma unroll
        for (int k = 0; k < IN; k++) acc += sx[r * IN + k] * sW[k * OUT + c];
        h[(size_t)node * OUT + c] = acc * sn[node];
    }
}

// ---------------- CSR gather aggregation: out = agg*dn + b (opt relu) ----------------
template <int OUT, int RELU>
__global__ void k_aggregate(const float* __restrict__ h, const int* __restrict__ off,
                            const int* __restrict__ edges, const float* __restrict__ dn,
                            const float* __restrict__ bias, float* __restrict__ out,
                            int col_off) {
    constexpr int NPB = 256 / OUT;
    int t = threadIdx.x;
    int g = t / OUT, c = t % OUT;
    int node = blockIdx.x * NPB + g;
    if (node >= NN) return;
    int e0 = off[node], e1 = off[node + 1];
    float acc = 0.0f;
    for (int e = e0; e < e1; e++) {
        int s = edges[e];
        acc += h[(size_t)s * OUT + c];
    }
    float v = acc * dn[node] + bias[c];
    if (RELU) v = fmaxf(v, 0.0f);
    out[(size_t)node * 48 + col_off + c] = v;
}

// ---------------- pooling v2: register-tiled lane-split-K GEMM ----------------
// pooled[b, colbase + j0 + n] += sum_k len[b,k] * H[k, j0+n]
// Wave tile: 8 graphs x 12 cols; lane l owns k = ks + 4l (+256 per step).
// acc[8][12] in registers; float4 loads only; butterfly reduce + atomics at end.
__global__ __launch_bounds__(256) void k_pool2(
        const float* __restrict__ lenA, const float* __restrict__ lenB,
        const float* __restrict__ HA, const float* __restrict__ HB,
        float* __restrict__ pooled) {
    const int mat = blockIdx.z;
    const float* __restrict__ len = mat ? lenB : lenA;
    const float* __restrict__ H   = mat ? HB : HA;
    const int colbase = mat ? 48 : 0;
    const int b0 = blockIdx.x * 8;
    const int w = threadIdx.x >> 6;      // wave id 0..3 -> col group
    const int l = threadIdx.x & 63;      // lane
    const int j0 = w * 12;

    float acc[8][12];
#pragma unroll
    for (int m = 0; m < 8; m++)
#pragma unroll
        for (int n = 0; n < 12; n++) acc[m][n] = 0.0f;

    const int kc0 = blockIdx.y * KCHUNK;
    const int kc1 = (kc0 + KCHUNK < NN) ? kc0 + KCHUNK : NN;

    for (int ks = kc0; ks < kc1; ks += 256) {
        int k = ks + 4 * l;
        float4 lq[8];
        float4 h[4][3];
        if (k < NN) {
            const float* lp = len + (size_t)b0 * NN + k;
#pragma unroll
            for (int m = 0; m < 8; m++)
                lq[m] = *(const float4*)(lp + (size_t)m * NN);
            const float* hp = H + (size_t)k * 48 + j0;
#pragma unroll
            for (int r = 0; r < 4; r++) {
                h[r][0] = *(const float4*)(hp + r * 48);
                h[r][1] = *(const float4*)(hp + r * 48 + 4);
                h[r][2] = *(const float4*)(hp + r * 48 + 8);
            }
        } else {
#pragma unroll
            for (int m = 0; m < 8; m++) lq[m] = make_float4(0.f, 0.f, 0.f, 0.f);
#pragma unroll
            for (int r = 0; r < 4; r++)
                h[r][0] = h[r][1] = h[r][2] = make_float4(0.f, 0.f, 0.f, 0.f);
        }
#pragma unroll
        for (int r = 0; r < 4; r++) {
            float4 h0 = h[r][0], h1 = h[r][1], h2 = h[r][2];
#pragma unroll
            for (int m = 0; m < 8; m++) {
                float lv = (r == 0) ? lq[m].x : (r == 1) ? lq[m].y : (r == 2) ? lq[m].z : lq[m].w;
                acc[m][0] += lv * h0.x;  acc[m][1] += lv * h0.y;
                acc[m][2] += lv * h0.z;  acc[m][3] += lv * h0.w;
                acc[m][4] += lv * h1.x;  acc[m][5] += lv * h1.y;
                acc[m][6] += lv * h1.z;  acc[m][7] += lv * h1.w;
                acc[m][8] += lv * h2.x;  acc[m][9] += lv * h2.y;
                acc[m][10] += lv * h2.z; acc[m][11] += lv * h2.w;
            }
        }
    }

    // butterfly reduce over 64 lanes, then one lane per (m,n) does the atomic
#pragma unroll
    for (int m = 0; m < 8; m++) {
#pragma unroll
        for (int n = 0; n < 12; n++) {
            float v = acc[m][n];
#pragma unroll
            for (int off = 32; off > 0; off >>= 1) v += __shfl_xor(v, off, 64);
            const int vid = m * 12 + n;
            if (l == (vid & 63))
                atomicAdd(&pooled[(b0 + m) * 96 + colbase + j0 + n], v);
        }
    }
}

// ---------------- MLP head ----------------
__global__ void k_mlp(const float* __restrict__ pooled,
                      const float* __restrict__ fc1w, const float* __restrict__ fc1b,
                      const float* __restrict__ fc2w, const float* __restrict__ fc2b,
                      const float* __restrict__ fc3w, const float* __restrict__ fc3b,
                      float* __restrict__ out) {
    __shared__ float srow[96];
    __shared__ float sh[64];
    __shared__ float sh2[16];
    int b = blockIdx.x, t = threadIdx.x; // 64 threads
    srow[t] = pooled[b * 96 + t];
    if (t < 32) srow[64 + t] = pooled[b * 96 + 64 + t];
    __syncthreads();
    float acc = fc1b[t];
    for (int k = 0; k < 96; k++) acc += srow[k] * fc1w[k * 64 + t];
    sh[t] = fmaxf(acc, 0.0f);
    __syncthreads();
    if (t < 16) {
        float a2 = fc2b[t];
        for (int k = 0; k < 64; k++) a2 += sh[k] * fc2w[k * 16 + t];
        sh2[t] = fmaxf(a2, 0.0f);
    }
    __syncthreads();
    if (t == 0) {
        float a3 = fc3b[0];
        for (int k = 0; k < 16; k++) a3 += sh2[k] * fc3w[k];
        out[b] = a3;
    }
}

extern "C" void kernel_launch(void* const* d_in, const int* in_sizes, int n_in,
                              void* d_out, int out_size, void* d_ws, size_t ws_size,
                              hipStream_t stream) {
    const float* solute_x  = (const float*)d_in[0];
    const float* solvent_x = (const float*)d_in[1];
    const float* su_len    = (const float*)d_in[2];
    const float* sv_len    = (const float*)d_in[3];
    const int*   su_src    = (const int*)d_in[4];
    const int*   su_dst    = (const int*)d_in[5];
    const int*   sv_src    = (const int*)d_in[6];
    const int*   sv_dst    = (const int*)d_in[7];
    const float* W1  = (const float*)d_in[8];
    const float* b1  = (const float*)d_in[9];
    const float* W2  = (const float*)d_in[10];
    const float* b2  = (const float*)d_in[11];
    const float* fc1w = (const float*)d_in[12];
    const float* fc1b = (const float*)d_in[13];
    const float* fc2w = (const float*)d_in[14];
    const float* fc2b = (const float*)d_in[15];
    const float* fc3w = (const float*)d_in[16];
    const float* fc3b = (const float*)d_in[17];
    float* out = (float*)d_out;

    // workspace layout (elements of 4 bytes)
    char* ws = (char*)d_ws;
    size_t o = 0;
    auto alloc = [&](size_t elems) { void* p = ws + o * 4; o += elems; return p; };
    void* degnorm   = alloc(4 * NN);          // int degrees -> float norms (in place)
    int* off_su     = (int*)alloc(NN + 64);
    int* off_sv     = (int*)alloc(NN + 64);
    int* cur_su     = (int*)alloc(NN);
    int* cur_sv     = (int*)alloc(NN);
    int* chunksum   = (int*)alloc(128);
    int* chunkoff   = (int*)alloc(160);
    int* edges_su   = (int*)alloc(NE);
    int* edges_sv   = (int*)alloc(NE);
    float* h_pre    = (float*)alloc(NN * 32);
    float* su_cat   = (float*)alloc((size_t)NN * 48);
    float* sv_cat   = (float*)alloc((size_t)NN * 48);
    float* pooled   = (float*)alloc(NB * 96);

    float* norm = (float*)degnorm;
    float* su_sn = norm + 0 * NN;
    float* su_dn = norm + 1 * NN;
    float* sv_sn = norm + 2 * NN;
    float* sv_dn = norm + 3 * NN;
    int* deg = (int*)degnorm;

    // zero degree counters and pooled accumulator
    hipMemsetAsync(degnorm, 0, 4 * NN * 4, stream);
    hipMemsetAsync(pooled, 0, NB * 96 * 4, stream);

    // degrees for all 4 index arrays
    {
        dim3 g(NE / 256, 4);
        k_degrees<<<g, 256, 0, stream>>>(su_src, su_dst, sv_src, sv_dst, deg);
    }
    // CSR offsets from dst degrees (before norms clobber deg)
    k_chunk_sum<<<NCHUNK, 256, 0, stream>>>(deg + 1 * NN, chunksum);
    k_chunk_scan<<<1, 64, 0, stream>>>(chunksum, chunkoff, off_su);
    k_scan_write<<<NCHUNK, 256, 0, stream>>>(deg + 1 * NN, chunkoff, off_su);
    k_chunk_sum<<<NCHUNK, 256, 0, stream>>>(deg + 3 * NN, chunksum);
    k_chunk_scan<<<1, 64, 0, stream>>>(chunksum, chunkoff, off_sv);
    k_scan_write<<<NCHUNK, 256, 0, stream>>>(deg + 3 * NN, chunkoff, off_sv);

    // degrees -> norms (in place, after scans consumed int degs)
    k_norms<<<(4 * NN + 255) / 256, 256, 0, stream>>>(degnorm);

    // CSR fill
    {
        dim3 g((NN + 255) / 256, 2);
        k_copy_cursor<<<g, 256, 0, stream>>>(off_su, off_sv, cur_su, cur_sv);
    }
    k_fill<<<NE / 256, 256, 0, stream>>>(su_src, su_dst, cur_su, edges_su);
    k_fill<<<NE / 256, 256, 0, stream>>>(sv_src, sv_dst, cur_sv, edges_sv);

    // ---- solute GCN ----
    k_transform<64, 32><<<(NN + 7) / 8, 256, 0, stream>>>(solute_x, 64, su_sn, W1, h_pre);
    k_aggregate<32, 1><<<(NN + 7) / 8, 256, 0, stream>>>(h_pre, off_su, edges_su, su_dn, b1, su_cat, 0);
    k_transform<32, 16><<<(NN + 15) / 16, 256, 0, stream>>>(su_cat, 48, su_sn, W2, h_pre);
    k_aggregate<16, 0><<<(NN + 15) / 16, 256, 0, stream>>>(h_pre, off_su, edges_su, su_dn, b2, su_cat, 32);

    // ---- solvent GCN ----
    k_transform<64, 32><<<(NN + 7) / 8, 256, 0, stream>>>(solvent_x, 64, sv_sn, W1, h_pre);
    k_aggregate<32, 1><<<(NN + 7) / 8, 256, 0, stream>>>(h_pre, off_sv, edges_sv, sv_dn, b1, sv_cat, 0);
    k_transform<32, 16><<<(NN + 15) / 16, 256, 0, stream>>>(sv_cat, 48, sv_sn, W2, h_pre);
    k_aggregate<16, 0><<<(NN + 15) / 16, 256, 0, stream>>>(h_pre, off_sv, edges_sv, sv_dn, b2, sv_cat, 32);

    // ---- fused pooling: both matrices, register-tiled split-K ----
    {
        dim3 g(NB / 8, NKC, 2);
        k_pool2<<<g, 256, 0, stream>>>(su_len, sv_len, su_cat, sv_cat, pooled);
    }

    // ---- MLP head ----
    k_mlp<<<NB, 64, 0, stream>>>(pooled, fc1w, fc1b, fc2w, fc2b, fc3w, fc3b, out);
}